// Round 1
// baseline (545.540 us; speedup 1.0000x reference)
//
#include <hip/hip_runtime.h>
#include <math.h>

// LearnableFlatPool: out[b,c,i,j] = max_{ki,kj} f[b,c,2i+ki,2j+kj] + h[c,ki,kj]
// h[c] = -((zi^2+zj^2)/t[c])^16 with zi in {-1,0,1}:
//   h matrix = [[corner,edge,corner],[edge,0,edge],[corner,edge,corner]]
//   edge = -(1/t)^16, corner = -(2/t)^16  (pow by squaring)

namespace {
constexpr int Bn = 16, Cn = 128, Hn = 224, Wn = 224;
constexpr int KS = 3, STRIDE = 2;
constexpr int Ho = (Hn - KS) / STRIDE + 1; // 111
constexpr int Wo = (Wn - KS) / STRIDE + 1; // 111
}

__global__ __launch_bounds__(256) void lfp_kernel(const float* __restrict__ f,
                                                  const float* __restrict__ t,
                                                  float* __restrict__ out) {
    const int j  = threadIdx.x;               // 0..127 -> output col (Wo=111)
    const int i  = blockIdx.y * 2 + threadIdx.y;
    const int bc = blockIdx.z;                // b*C + c
    const int c  = bc & (Cn - 1);             // C=128 power of two

    // Per-channel h values, uniform across the block (compiler scalarizes).
    const float tc = t[c];
    const float xe = 1.0f / tc;
    const float xc = 2.0f / tc;
    float e2 = xe * xe, e4 = e2 * e2, e8 = e4 * e4;
    float c2 = xc * xc, c4 = c2 * c2, c8 = c4 * c4;
    const float h_edge   = -(e8 * e8);
    const float h_corner = -(c8 * c8);

    if (i >= Ho || j >= Wo) return;

    const float* base = f + ((size_t)bc * Hn + (size_t)(2 * i)) * Wn + 2 * j;

    float m = -INFINITY;
#pragma unroll
    for (int ki = 0; ki < 3; ++ki) {
        const float2 v = *(const float2*)(base + (size_t)ki * Wn); // cols 2j, 2j+1
        const float  w = base[(size_t)ki * Wn + 2];                // col 2j+2
        const float hA = (ki == 1) ? h_edge : h_corner;            // kj = 0, 2
        const float hB = (ki == 1) ? 0.0f   : h_edge;              // kj = 1
        float rm = fmaxf(fmaxf(v.x + hA, v.y + hB), w + hA);
        m = fmaxf(m, rm);
    }
    out[((size_t)bc * Ho + i) * Wo + j] = m;
}

extern "C" void kernel_launch(void* const* d_in, const int* in_sizes, int n_in,
                              void* d_out, int out_size, void* d_ws, size_t ws_size,
                              hipStream_t stream) {
    const float* f = (const float*)d_in[0];
    const float* t = (const float*)d_in[1];
    float* out = (float*)d_out;

    dim3 block(128, 2, 1);
    dim3 grid(1, (Ho + 1) / 2, Bn * Cn); // (1, 56, 2048)
    lfp_kernel<<<grid, block, 0, stream>>>(f, t, out);
}